// Round 5
// baseline (285.208 us; speedup 1.0000x reference)
//
#include <hip/hip_runtime.h>
#include <stdint.h>

constexpr int BATCH  = 2048;
constexpr int NHID   = 512;
constexpr int H0     = 256;
constexpr int H1     = 256;
constexpr int SMAX   = 16;           // tile capacity (P(n>16) ~ 0.4%)
constexpr int KSTEP  = 8;            // K-rows per pipeline step
constexpr int NSTEPS = NHID / KSTEP; // 64
constexpr int NBUF   = 4;            // LDS ring buffers (stage 3 ahead)

// async global->LDS, 16B per lane; LDS dest must be wave-uniform base
// (HW adds lane*16), global src is per-lane.
__device__ __forceinline__ void gload_lds16(const float* gsrc, float* ldst) {
    __builtin_amdgcn_global_load_lds(
        (const __attribute__((address_space(1))) void*)gsrc,
        (__attribute__((address_space(3))) void*)ldst, 16, 0, 0);
}

#define FMA4(xc, wr) \
    a.x = fmaf((xc), (wr).x, a.x); a.y = fmaf((xc), (wr).y, a.y); \
    a.z = fmaf((xc), (wr).z, a.z); a.w = fmaf((xc), (wr).w, a.w)

// One block per parent p (grid = 256 = 1 block/CU), 512 threads = 8 waves.
// Waves 0-3 = bottom pass, waves 4-7 = top pass; wave ws owns nsl (2 or 4)
// full-depth samples, lane l owns output cols 4l..4l+3 (acc = 4 float4).
// No K-split -> no cross-wave reduction. W streamed through a 4-buffer LDS
// ring via global_load_lds staged 3 K-steps ahead with counted vmcnt(4)
// (never 0 in the main loop): ~2000 cyc of load cover vs the 8-float4
// register ring's ~500 (the rounds-0/1 latency wall). Register footprint
// ~110 VGPRs, safely under the allocator's 128 cap (rounds 2-4 spill bug).
__global__ __launch_bounds__(512) void hs_v5(
    const float* __restrict__ x,        // [B, NHID]
    const int*   __restrict__ labels,   // [B]
    const int*   __restrict__ parents,  // [B]
    const float* __restrict__ topW,     // [NHID, H0]
    const float* __restrict__ topb,     // [H0]
    const float* __restrict__ botW,     // [H0, NHID, H1]
    const float* __restrict__ botb,     // [H0, H1]
    float*       __restrict__ out)      // [B]
{
    const int p  = blockIdx.x;
    const int t  = threadIdx.x;        // 0..511
    const int g  = t >> 6;             // wave 0..7
    const int l  = t & 63;
    const int ws = g & 3;              // sample-group index within pass
    const bool bot = (g < 4);

    __shared__ int list[BATCH];                        // 8 KB
    __shared__ int wcnt[8];
    __shared__ __align__(16) float xs[SMAX][NHID];     // 32 KB
    __shared__ __align__(16) float Wb[NBUF][KSTEP][H1];// 32 KB
    __shared__ __align__(16) float Wt[NBUF][KSTEP][H0];// 32 KB
    __shared__ float psm[2][SMAX];                     // total ~104.2 KB

    // ---- deterministic list build (ballot prefix scan, verified r1-r4)
    int running = 0;
    for (int c = 0; c < BATCH; c += 512) {
        const bool match = (parents[c + t] == p);
        const unsigned long long mask = __ballot(match);
        if (l == 0) wcnt[g] = __popcll(mask);
        __syncthreads();
        int off = running;
        #pragma unroll
        for (int w = 0; w < 8; ++w) {
            const int cw = wcnt[w];
            if (w < g) off += cw;
            running += cw;
        }
        if (match)
            list[off + __popcll(mask & ((1ull << l) - 1ull))] = c + t;
        __syncthreads();   // wcnt reused next chunk
    }
    const int n = running;
    if (n == 0) return;    // uniform exit (before any raw barrier)

    const float* botWp = botW + (size_t)p * NHID * H1;
    const float4 b4 = bot ? *(const float4*)(botb + (size_t)p * H1 + 4 * l)
                          : *(const float4*)(topb + 4 * l);

    // wave g stages 1KB chunk g of the 8KB bot tile AND of the 8KB top tile
    // for K-step kk. LDS dest uniform within wave; global src per-lane.
    #define STAGE(kk) do {                                                   \
        const int _b = (kk) & (NBUF - 1);                                    \
        gload_lds16(botWp + (size_t)(kk) * (KSTEP * H1) + g * 256 + l * 4,   \
                    &Wb[_b][0][0] + g * 256);                                \
        gload_lds16(topW  + (size_t)(kk) * (KSTEP * H0) + g * 256 + l * 4,   \
                    &Wt[_b][0][0] + g * 256);                                \
    } while (0)

    for (int base = 0; base < n; base += SMAX) {   // normally exactly 1 tile
        const int rem  = min(SMAX, n - base);
        const bool hi  = (rem > 8);                // block-uniform
        const int nsl  = hi ? 4 : 2;               // samples per wave
        const int nrow = hi ? 16 : 8;

        // ---- stage x rows (padded slots replicate last real sample)
        for (int s0 = 0; s0 < nrow; s0 += 4) {
            const int row = s0 + (t >> 7);
            const int idx = list[base + min(row, rem - 1)];
            ((float4*)xs[row])[t & 127] =
                ((const float4*)(x + (size_t)idx * NHID))[t & 127];
        }
        __syncthreads();   // xs ready; also drains vmcnt to 0 (clean count)

        float4 acc[4];
        #pragma unroll
        for (int i = 0; i < 4; ++i) acc[i] = make_float4(0.f, 0.f, 0.f, 0.f);

        // ---- pipeline prologue: 3 K-steps in flight (6 loads/wave)
        STAGE(0); STAGE(1); STAGE(2);

        for (int k = 0; k < NSTEPS; ++k) {
            // counted waits: 2 loads/wave/step; keep 2 future steps in
            // flight mid-loop (vmcnt(4)), drain only at the very end.
            if (k <= NSTEPS - 3)
                asm volatile("s_waitcnt vmcnt(4)" ::: "memory");
            else if (k == NSTEPS - 2)
                asm volatile("s_waitcnt vmcnt(2)" ::: "memory");
            else
                asm volatile("s_waitcnt vmcnt(0)" ::: "memory");
            __builtin_amdgcn_s_barrier();      // all waves' chunks arrived;
            asm volatile("" ::: "memory");     // and all finished step k-1

            if (k + 3 < NSTEPS) STAGE(k + 3);  // overwrites buf[(k-1)&3]:
                                               // safe only after the barrier

            const int buf = k & (NBUF - 1);
            // W rows from LDS: lanes read 1KB consecutive -> conflict-free
            const float* Wl = bot ? &Wb[0][0][0] : &Wt[0][0][0];
            float4 wrow[KSTEP];
            #pragma unroll
            for (int r = 0; r < KSTEP; ++r)
                wrow[r] = *(const float4*)(Wl + (buf * KSTEP + r) * 256 + 4 * l);

            // xv: wave-uniform broadcast reads, batched before the FMAs
            float4 xa[4], xb[4];
            #pragma unroll
            for (int i = 0; i < 4; ++i) if (i < nsl) {
                const int slot = nsl * ws + i;
                xa[i] = *(const float4*)&xs[slot][KSTEP * k];
                xb[i] = *(const float4*)&xs[slot][KSTEP * k + 4];
            }
            #pragma unroll
            for (int i = 0; i < 4; ++i) if (i < nsl) {
                float4 a = acc[i];
                FMA4(xa[i].x, wrow[0]); FMA4(xa[i].y, wrow[1]);
                FMA4(xa[i].z, wrow[2]); FMA4(xa[i].w, wrow[3]);
                FMA4(xb[i].x, wrow[4]); FMA4(xb[i].y, wrow[5]);
                FMA4(xb[i].z, wrow[6]); FMA4(xb[i].w, wrow[7]);
                acc[i] = a;
            }
        }

        // ---- wave-local softmax per owned sample (verified pattern)
        #pragma unroll
        for (int i = 0; i < 4; ++i) if (i < nsl) {
            const int slot = nsl * ws + i;
            float4 v = acc[i];
            v.x += b4.x; v.y += b4.y; v.z += b4.z; v.w += b4.w;

            float m = fmaxf(fmaxf(v.x, v.y), fmaxf(v.z, v.w));
            #pragma unroll
            for (int off = 32; off > 0; off >>= 1)
                m = fmaxf(m, __shfl_xor(m, off, 64));

            const float ex = expf(v.x - m), ey = expf(v.y - m);
            const float ez = expf(v.z - m), ew = expf(v.w - m);
            float sum = (ex + ey) + (ez + ew);
            #pragma unroll
            for (int off = 32; off > 0; off >>= 1)
                sum += __shfl_xor(sum, off, 64);

            const int tgt = bot ? labels[list[base + min(slot, rem - 1)]] : p;
            const int kc  = tgt & 3;
            const float ev = (kc == 0) ? ex : (kc == 1) ? ey
                           : (kc == 2) ? ez : ew;
            if (l == (tgt >> 2))
                psm[bot ? 1 : 0][slot] = ev / sum;
        }
        __syncthreads();   // psm complete

        if (t < rem) {
            const int idx = list[base + t];
            out[idx] = psm[0][t] * psm[1][t];
        }
        __syncthreads();   // xs/psm/W bufs safe to overwrite next tile
    }
    #undef STAGE
}

extern "C" void kernel_launch(void* const* d_in, const int* in_sizes, int n_in,
                              void* d_out, int out_size, void* d_ws, size_t ws_size,
                              hipStream_t stream) {
    const float* x       = (const float*)d_in[0];
    const int*   labels  = (const int*)  d_in[1];
    const int*   parents = (const int*)  d_in[2];
    const float* topW    = (const float*)d_in[3];
    const float* topb    = (const float*)d_in[4];
    const float* botW    = (const float*)d_in[5];
    const float* botb    = (const float*)d_in[6];
    float*       out     = (float*)d_out;

    hs_v5<<<H0, 512, 0, stream>>>(x, labels, parents,
                                  topW, topb, botW, botb, out);
}

// Round 8
// 229.193 us; speedup vs baseline: 1.2444x; 1.2444x over previous
//
#include <hip/hip_runtime.h>

constexpr int BATCH = 2048;
constexpr int NHID  = 512;
constexpr int H0    = 256;
constexpr int H1    = 256;
constexpr int S     = 8;    // samples per tile
constexpr int J     = 3;    // tile-slot blocks per parent (grid = 256*J)

// Round-0 verified kernel + ONE change: per h-step, the 8 xv broadcast
// ds_reads are batched into registers BEFORE the FMA block (critical path
// ~120+8*12+256 cyc instead of 8*(120+32) serialized chains). 8-sample tile
// keeps register demand at ~acc(32)+xv(32)+ring(32)+misc ~= 112 VGPRs --
// under the allocator's hard 128 cap that spilled the 16-sample attempts
// (rounds 2-4). Everything else (list build, softmax, FP order) identical
// to round 0 -> absmax 0.0 expected.
__global__ __launch_bounds__(128) void hs_8sb(
    const float* __restrict__ x,        // [B, NHID]
    const int*   __restrict__ labels,   // [B]
    const int*   __restrict__ parents,  // [B]
    const float* __restrict__ topW,     // [NHID, H0]
    const float* __restrict__ topb,     // [H0]
    const float* __restrict__ botW,     // [H0, NHID, H1]
    const float* __restrict__ botb,     // [H0, H1]
    float*       __restrict__ out)      // [B]
{
    const int p = blockIdx.x / J;
    const int j = blockIdx.x % J;
    const int t = threadIdx.x;        // 0..127
    const int g = t >> 6;             // wave 0 = top, wave 1 = bottom
    const int l = t & 63;

    __shared__ int   list[BATCH];                   // 8 KB
    __shared__ int   wcnt[2];
    __shared__ __align__(16) float xs[S][NHID];     // 16 KB
    __shared__ float psm[2][S];

    // ---- deterministic ordered list build (ballot prefix scan)
    int running = 0;
    for (int c = 0; c < BATCH; c += 128) {
        const bool match = (parents[c + t] == p);
        const unsigned long long mask = __ballot(match);
        if (l == 0) wcnt[g] = __popcll(mask);
        __syncthreads();
        const int off = running + (g ? wcnt[0] : 0);
        if (match)
            list[off + __popcll(mask & ((1ull << l) - 1ull))] = c + t;
        running += wcnt[0] + wcnt[1];
        __syncthreads();   // wcnt reused next chunk
    }
    const int n = running;
    if (n <= j * S) return;   // uniform exit

    const float* Wbase = g ? botW + (size_t)p * NHID * H1 : topW;
    const float4 b4    = g ? *(const float4*)(botb + (size_t)p * H1 + 4 * l)
                           : *(const float4*)(topb + 4 * l);

    for (int base = j * S; base < n; base += J * S) {
        const int rem = min(S, n - base);

        // ---- stage 8 x-rows (padded slots replicate last); 1 float4/thr/row
        for (int s = 0; s < S; ++s) {
            const int idx = list[base + min(s, rem - 1)];
            ((float4*)xs[s])[t] = ((const float4*)(x + (size_t)idx * NHID))[t];
        }

        // per-sample softmax targets (wave-uniform)
        int tgts[S];
        #pragma unroll
        for (int s = 0; s < S; ++s) {
            const int slot = base + min(s, rem - 1);
            tgts[s] = g ? labels[list[slot]] : p;
        }
        __syncthreads();   // xs ready

        // ---- full-depth register GEMV: 8 samples, 4 classes/lane
        float4 acc[S];
        #pragma unroll
        for (int s = 0; s < S; ++s) acc[s] = make_float4(0.f, 0.f, 0.f, 0.f);

        const float* Wp = Wbase + 4 * l;
        float4 ring[8];
        #pragma unroll
        for (int i = 0; i < 8; ++i)
            ring[i] = *(const float4*)(Wp + (size_t)i * H0);

        for (int d = 0; d < NHID; d += 8) {
            #pragma unroll
            for (int h = 0; h < 2; ++h) {
                const int dd = d + 4 * h;
                const float4 w0 = ring[4 * h + 0], w1 = ring[4 * h + 1];
                const float4 w2 = ring[4 * h + 2], w3 = ring[4 * h + 3];

                // issue next-group global refills first (fly under ds_reads)
                if (dd + 8 < NHID) {
                    #pragma unroll
                    for (int i = 0; i < 4; ++i)
                        ring[4 * h + i] =
                            *(const float4*)(Wp + (size_t)(dd + 8 + i) * H0);
                }

                // batch ALL 8 xv broadcast reads before any dependent FMA
                float4 xv[S];
                #pragma unroll
                for (int s = 0; s < S; ++s)
                    xv[s] = *(const float4*)&xs[s][dd];

                #pragma unroll
                for (int s = 0; s < S; ++s) {
                    const float4 xv4 = xv[s];
                    float4 a = acc[s];
                    a.x = fmaf(xv4.x, w0.x, a.x); a.y = fmaf(xv4.x, w0.y, a.y);
                    a.z = fmaf(xv4.x, w0.z, a.z); a.w = fmaf(xv4.x, w0.w, a.w);
                    a.x = fmaf(xv4.y, w1.x, a.x); a.y = fmaf(xv4.y, w1.y, a.y);
                    a.z = fmaf(xv4.y, w1.z, a.z); a.w = fmaf(xv4.y, w1.w, a.w);
                    a.x = fmaf(xv4.z, w2.x, a.x); a.y = fmaf(xv4.z, w2.y, a.y);
                    a.z = fmaf(xv4.z, w2.z, a.z); a.w = fmaf(xv4.z, w2.w, a.w);
                    a.x = fmaf(xv4.w, w3.x, a.x); a.y = fmaf(xv4.w, w3.y, a.y);
                    a.z = fmaf(xv4.w, w3.z, a.z); a.w = fmaf(xv4.w, w3.w, a.w);
                    acc[s] = a;
                }
            }
        }

        // ---- wave-local softmax per sample (R5-verified)
        #pragma unroll
        for (int s = 0; s < S; ++s) {
            float4 v = acc[s];
            v.x += b4.x; v.y += b4.y; v.z += b4.z; v.w += b4.w;

            float m = fmaxf(fmaxf(v.x, v.y), fmaxf(v.z, v.w));
            #pragma unroll
            for (int off = 32; off > 0; off >>= 1)
                m = fmaxf(m, __shfl_xor(m, off, 64));

            const float ex = expf(v.x - m), ey = expf(v.y - m);
            const float ez = expf(v.z - m), ew = expf(v.w - m);
            float sum = (ex + ey) + (ez + ew);
            #pragma unroll
            for (int off = 32; off > 0; off >>= 1)
                sum += __shfl_xor(sum, off, 64);

            const int tgt = tgts[s];           // wave-uniform
            const int k   = tgt & 3;
            const float ev = (k == 0) ? ex : (k == 1) ? ey : (k == 2) ? ez : ew;
            if (l == (tgt >> 2))
                psm[g][s] = ev / sum;
        }
        __syncthreads();   // psm complete

        if (t < rem) {
            const int idx = list[base + t];
            out[idx] = psm[0][t] * psm[1][t];
        }
        __syncthreads();   // xs/psm safe to overwrite next tile
    }
}

extern "C" void kernel_launch(void* const* d_in, const int* in_sizes, int n_in,
                              void* d_out, int out_size, void* d_ws, size_t ws_size,
                              hipStream_t stream) {
    const float* x       = (const float*)d_in[0];
    const int*   labels  = (const int*)  d_in[1];
    const int*   parents = (const int*)  d_in[2];
    const float* topW    = (const float*)d_in[3];
    const float* topb    = (const float*)d_in[4];
    const float* botW    = (const float*)d_in[5];
    const float* botb    = (const float*)d_in[6];
    float*       out     = (float*)d_out;

    hs_8sb<<<H0 * J, 128, 0, stream>>>(x, labels, parents,
                                       topW, topb, botW, botb, out);
}